// Round 7
// baseline (10187.479 us; speedup 1.0000x reference)
//
#include <hip/hip_runtime.h>
#include <hip/hip_bf16.h>

// BISECTION ROUND: all-f32 VALU GEMM (no MFMA, no f16) + attention kernels
// byte-identical to round 6. Isolates whether the residual 4.85e-2 error lives
// in the MFMA/f16 projection path or in the attention path.
// Shapes: B=8 S=1569 D=768 NH=12 DH=64 NCLS=1 BS=49 M=32 NKV=6

#define S_TOT   1569
#define NCOL    2304          // 3*768
#define NBATCH  8

typedef unsigned short u16;

// -------- conv_w: Wq/Wk/Wv (768x768 f32) -> Wtf (2304x768 f32), Wtf[n][d] = W[d][n]
__global__ __launch_bounds__(256) void conv_w(const float* __restrict__ Wq,
                                              const float* __restrict__ Wk,
                                              const float* __restrict__ Wv,
                                              float* __restrict__ Wtf) {
    __shared__ float tile[32][33];
    int n0 = blockIdx.x * 32;          // 0..2303
    int d0 = blockIdx.y * 32;          // 0..767
    int tx = threadIdx.x & 31, ty = threadIdx.x >> 5;   // 32 x 8
    int which = n0 / 768;
    int nn0 = n0 - which * 768;
    const float* W = (which == 0) ? Wq : (which == 1 ? Wk : Wv);
#pragma unroll
    for (int k = 0; k < 4; k++)
        tile[ty + 8 * k][tx] = W[(d0 + ty + 8 * k) * 768 + nn0 + tx];
    __syncthreads();
#pragma unroll
    for (int k = 0; k < 4; k++)
        Wtf[(n0 + ty + 8 * k) * 768 + d0 + tx] = tile[tx][ty + 8 * k];
}

// -------- gemm_simple: one token per block.x, 128 output cols per block.y
// C[t,n] = sum_d X[t,d] * Wtf[n,d]  (all f32, trivially correct)
__global__ __launch_bounds__(128) void gemm_simple(const float* __restrict__ X,
                                                   const float* __restrict__ Wtf,
                                                   const float* __restrict__ bq,
                                                   const float* __restrict__ bv,
                                                   float* __restrict__ Q,
                                                   float* __restrict__ K,
                                                   float* __restrict__ V,
                                                   int b0, int nTok) {
    __shared__ float xs[768];
    int t = blockIdx.x;
    if (t >= nTok) return;
    int n = blockIdx.y * 128 + threadIdx.x;       // 0..2303
    const float* Xb = X + (size_t)b0 * S_TOT * 768;

    for (int i = threadIdx.x; i < 192; i += 128)
        ((float4*)xs)[i] = ((const float4*)(Xb + (size_t)t * 768))[i];
    __syncthreads();

    const float4* wr4 = (const float4*)(Wtf + (size_t)n * 768);
    float a = 0.f;
#pragma unroll 4
    for (int d4 = 0; d4 < 192; d4++) {
        float4 xv = ((const float4*)xs)[d4];
        float4 wv = wr4[d4];
        a = fmaf(xv.x, wv.x, a); a = fmaf(xv.y, wv.y, a);
        a = fmaf(xv.z, wv.z, a); a = fmaf(xv.w, wv.w, a);
    }

    float* dst;
    int nn;
    if (n < 768)       { dst = Q; nn = n;        a += bq[nn]; }
    else if (n < 1536) { dst = K; nn = n - 768;                }
    else               { dst = V; nn = n - 1536; a += bv[nn];  }
    int bl = t / S_TOT;
    int s = t - bl * S_TOT;
    int h = nn >> 6, d = nn & 63;
    dst[((bl * 12 + h) * S_TOT + s) * 64 + d] = a;
}

// -------- cls attention: 1 query per (bl,h) over all S keys  [identical to R6]
__global__ __launch_bounds__(256) void cls_attn(const float* __restrict__ Q,
                                                const float* __restrict__ K,
                                                const float* __restrict__ V,
                                                const float* __restrict__ rel,
                                                const int* __restrict__ rpi,
                                                float* __restrict__ out, int b0) {
    int bh = blockIdx.x;               // bl*12 + h
    int bl = bh / 12, h = bh - bl * 12;
    __shared__ float p[S_TOT];
    __shared__ float4 qs4[16];
    __shared__ float red[256];
    __shared__ float wred[8];
    int tid = threadIdx.x, lane = tid & 63, w = tid >> 6;
    size_t base = (size_t)bh * S_TOT * 64;
    const float* Qb = Q + base;
    const float* Kb = K + base;
    const float* Vb = V + base;
    if (tid < 64) ((float*)qs4)[tid] = Qb[tid];
    __syncthreads();

    float lmx = -1e30f;
    for (int j = tid; j < S_TOT; j += 256) {
        const float4* kr = (const float4*)(Kb + j * 64);
        float a = 0.f;
#pragma unroll
        for (int d4 = 0; d4 < 16; d4++) {
            float4 kv = kr[d4];
            float4 qv = qs4[d4];
            a = fmaf(qv.x, kv.x, a); a = fmaf(qv.y, kv.y, a);
            a = fmaf(qv.z, kv.z, a); a = fmaf(qv.w, kv.w, a);
        }
        a = a * 0.125f + rel[rpi[j] * 12 + h];
        p[j] = a;
        lmx = fmaxf(lmx, a);
    }
#pragma unroll
    for (int off = 32; off > 0; off >>= 1) lmx = fmaxf(lmx, __shfl_xor(lmx, off));
    if (lane == 0) wred[w] = lmx;
    __syncthreads();
    float mx = fmaxf(fmaxf(wred[0], wred[1]), fmaxf(wred[2], wred[3]));
    float lsum = 0.f;
    for (int j = tid; j < S_TOT; j += 256) {
        float e = __expf(p[j] - mx);
        p[j] = e;
        lsum += e;
    }
#pragma unroll
    for (int off = 32; off > 0; off >>= 1) lsum += __shfl_xor(lsum, off);
    if (lane == 0) wred[4 + w] = lsum;
    __syncthreads();
    float inv = 1.0f / (wred[4] + wred[5] + wred[6] + wred[7]);
    float acc = 0.f;
    for (int j = w; j < S_TOT; j += 4) acc = fmaf(p[j], Vb[j * 64 + lane], acc);
    red[w * 64 + lane] = acc;
    __syncthreads();
    if (w == 0) {
        float o = (red[lane] + red[64 + lane] + red[128 + lane] + red[192 + lane]) * inv;
        out[(size_t)(b0 + bl) * S_TOT * 768 + h * 64 + lane] = o;
    }
}

// -------- block-sparse local attention: one wg per (m, h, bl)  [identical to R6]
__global__ __launch_bounds__(256) void loc_attn(const float* __restrict__ Q,
                                                const float* __restrict__ K,
                                                const float* __restrict__ V,
                                                const float* __restrict__ rel,
                                                const int* __restrict__ rpi,
                                                const int* __restrict__ rand_idx,
                                                float* __restrict__ out, int b0) {
    int m = blockIdx.x;    // 0..31
    int h = blockIdx.y;    // 0..11
    int bl = blockIdx.z;   // 0..cb-1
    __shared__ float sim[52 * 295];     // rows 49..51 zeroed scratch
    __shared__ int   tok[295];
    __shared__ float rs[49];
    int tid = threadIdx.x, lane = tid & 63, w = tid >> 6;
    int nrows = (w == 0) ? 13 : 12;     // rows i = w + 4r, i < 49

    for (int jj = tid; jj < 295; jj += 256) {
        int t;
        if (jj == 0) t = 0;             // cls token
        else {
            int j1 = jj - 1;
            int n = j1 / 49;
            int q = j1 - n * 49;
            int a;
            if (n == 0)      a = (m + 31) & 31;
            else if (n == 1) a = m;
            else if (n == 2) a = (m + 1) & 31;
            else             a = rand_idx[m * 3 + (n - 3)];
            t = 1 + a * 49 + q;
        }
        tok[jj] = t;
    }
    for (int z = tid; z < 3 * 295; z += 256) sim[49 * 295 + z] = 0.f;
    __syncthreads();

    size_t base = (size_t)((bl * 12 + h) * S_TOT) * 64;
    const float* Qb = Q + base;
    const float* Kb = K + base;
    const float* Vb = V + base;

    // ---- QK^T + bias -> sim
    for (int jc = 0; jc < 5; jc++) {
        int j = jc * 64 + lane;
        bool jv = j < 295;
        int tj = jv ? tok[j] : 0;
        const float4* krow = (const float4*)(Kb + tj * 64);
        float4 kf[16];
#pragma unroll
        for (int d4 = 0; d4 < 16; d4++) kf[d4] = krow[d4];
        for (int r = 0; r < nrows; r++) {
            int i = w + 4 * r;
            int qr = 1 + m * 49 + i;
            const float4* qrow = (const float4*)(Qb + qr * 64);
            float a = 0.f;
#pragma unroll
            for (int d4 = 0; d4 < 16; d4++) {
                float4 qv = qrow[d4];
                float4 kv = kf[d4];
                a = fmaf(qv.x, kv.x, a); a = fmaf(qv.y, kv.y, a);
                a = fmaf(qv.z, kv.z, a); a = fmaf(qv.w, kv.w, a);
            }
            if (jv) {
                float sv = a * 0.125f + rel[rpi[qr * S_TOT + tj] * 12 + h];
                sim[i * 295 + j] = sv;
            }
        }
    }
    __syncthreads();

    // ---- softmax per row (one wave per row-group)
    for (int r = 0; r < nrows; r++) {
        int i = w + 4 * r;
        float mx = -1e30f;
#pragma unroll
        for (int jc = 0; jc < 5; jc++) {
            int j = jc * 64 + lane;
            if (j < 295) mx = fmaxf(mx, sim[i * 295 + j]);
        }
#pragma unroll
        for (int off = 32; off > 0; off >>= 1) mx = fmaxf(mx, __shfl_xor(mx, off));
        float sum = 0.f;
#pragma unroll
        for (int jc = 0; jc < 5; jc++) {
            int j = jc * 64 + lane;
            if (j < 295) {
                float e = __expf(sim[i * 295 + j] - mx);
                sim[i * 295 + j] = e;
                sum += e;
            }
        }
#pragma unroll
        for (int off = 32; off > 0; off >>= 1) sum += __shfl_xor(sum, off);
        if (lane == 0) rs[i] = 1.0f / sum;
    }
    __syncthreads();

    // ---- PV: lane = d, each wave owns rows w+4r (facc[12] of w>0 reads zeroed scratch)
    float facc[13];
#pragma unroll
    for (int r = 0; r < 13; r++) facc[r] = 0.f;
    for (int j = 0; j < 295; j++) {
        float vv = Vb[tok[j] * 64 + lane];
#pragma unroll
        for (int r = 0; r < 13; r++)
            facc[r] = fmaf(sim[(w + 4 * r) * 295 + j], vv, facc[r]);
    }
    for (int r = 0; r < nrows; r++) {
        int i = w + 4 * r;
        int s = 1 + m * 49 + i;
        out[((size_t)(b0 + bl) * S_TOT + s) * 768 + h * 64 + lane] = facc[r] * rs[i];
    }
}

extern "C" void kernel_launch(void* const* d_in, const int* in_sizes, int n_in,
                              void* d_out, int out_size, void* d_ws, size_t ws_size,
                              hipStream_t stream) {
    (void)in_sizes; (void)n_in; (void)out_size;
    const float* hs  = (const float*)d_in[0];
    const float* Wq  = (const float*)d_in[1];
    const float* bq  = (const float*)d_in[2];
    const float* Wk  = (const float*)d_in[3];
    const float* Wv  = (const float*)d_in[4];
    const float* bv  = (const float*)d_in[5];
    const float* rel = (const float*)d_in[6];
    const int*   rpi = (const int*)d_in[7];
    const int*   rnd = (const int*)d_in[8];
    float* out = (float*)d_out;
    char* ws = (char*)d_ws;

    // workspace: Wtf f32 (2304x768) | f32 Q/K/V (12*1569*64 per batch each)
    constexpr size_t WT_OFF  = 0;
    constexpr size_t QKV_OFF = (size_t)NCOL * 768 * 4;               // 7,077,888
    constexpr size_t PBUF    = (size_t)12 * S_TOT * 64 * 4;          // 4,819,968

    float* Wtf = (float*)(ws + WT_OFF);

    int C = 1;
    if (ws_size > QKV_OFF + 3 * PBUF) {
        size_t c = (ws_size - QKV_OFF) / (3 * PBUF);
        C = (c >= NBATCH) ? NBATCH : (int)c;
        if (C < 1) C = 1;
    }
    float* Q = (float*)(ws + QKV_OFF);
    float* K = (float*)(ws + QKV_OFF + (size_t)C * PBUF);
    float* V = (float*)(ws + QKV_OFF + (size_t)C * PBUF * 2);

    conv_w<<<dim3(72, 24), dim3(256), 0, stream>>>(Wq, Wk, Wv, Wtf);

    for (int b0 = 0; b0 < NBATCH; b0 += C) {
        int cb = (NBATCH - b0 < C) ? (NBATCH - b0) : C;
        int nTok = cb * S_TOT;
        gemm_simple<<<dim3(nTok, NCOL / 128), dim3(128), 0, stream>>>(
            hs, Wtf, bq, bv, Q, K, V, b0, nTok);
        cls_attn<<<dim3(12 * cb), dim3(256), 0, stream>>>(Q, K, V, rel, rpi, out, b0);
        loc_attn<<<dim3(32, 12, cb), dim3(256), 0, stream>>>(Q, K, V, rel, rpi, rnd, out, b0);
    }
}

// Round 8
// 3156.425 us; speedup vs baseline: 3.2275x; 3.2275x over previous
//
#include <hip/hip_runtime.h>
#include <hip/hip_bf16.h>

// BeitSelfAttention — self-healing round.
// MFMA-f16 QKV GEMM + on-device f32 verification (6 sampled 64-token slabs, all cols)
// + full f32 tiled repair GEMM that early-exits if verification passed.
// Attention kernels byte-identical to the PASSING round 7.
// Shapes: B=8 S=1569 D=768 NH=12 DH=64 NCLS=1 BS=49 M=32 NKV=6

#define S_TOT   1569
#define NCOL    2304          // 3*768
#define NBATCH  8
#define NX      9637632       // 8*1569*768

typedef __attribute__((ext_vector_type(8))) _Float16 f16x8;
typedef __attribute__((ext_vector_type(4))) float f32x4;
typedef unsigned short u16;

static __device__ __forceinline__ u16 f2h(float x) {
    _Float16 h = (_Float16)x;
    return __builtin_bit_cast(u16, h);
}
static __device__ __forceinline__ unsigned int pack2h(float lo, float hi) {
    return (unsigned int)f2h(lo) | ((unsigned int)f2h(hi) << 16);
}

__global__ void init_flag(int* flag) { *flag = 0; }

// -------- conv_x: hidden_states f32 -> Xh f16
__global__ __launch_bounds__(256) void conv_x(const float* __restrict__ hs,
                                              u16* __restrict__ Xh) {
    int v = blockIdx.x * 256 + threadIdx.x;
    if (v >= NX / 8) return;
    const float4* src = (const float4*)hs + 2 * (size_t)v;
    float4 x0 = src[0], x1 = src[1];
    uint4 av;
    av.x = pack2h(x0.x, x0.y);
    av.y = pack2h(x0.z, x0.w);
    av.z = pack2h(x1.x, x1.y);
    av.w = pack2h(x1.z, x1.w);
    ((uint4*)Xh)[v] = av;
}

// -------- conv_w2: W (768x768 f32 x3) -> Wtf f32 (2304x768, W^T) AND Wt f16
__global__ __launch_bounds__(256) void conv_w2(const float* __restrict__ Wq,
                                               const float* __restrict__ Wk,
                                               const float* __restrict__ Wv,
                                               float* __restrict__ Wtf,
                                               u16* __restrict__ Wt) {
    __shared__ float tile[32][33];
    int n0 = blockIdx.x * 32;
    int d0 = blockIdx.y * 32;
    int tx = threadIdx.x & 31, ty = threadIdx.x >> 5;
    int which = n0 / 768;
    int nn0 = n0 - which * 768;
    const float* W = (which == 0) ? Wq : (which == 1 ? Wk : Wv);
#pragma unroll
    for (int k = 0; k < 4; k++)
        tile[ty + 8 * k][tx] = W[(d0 + ty + 8 * k) * 768 + nn0 + tx];
    __syncthreads();
#pragma unroll
    for (int k = 0; k < 4; k++) {
        float v = tile[tx][ty + 8 * k];
        int idx = (n0 + ty + 8 * k) * 768 + d0 + tx;
        Wtf[idx] = v;
        Wt[idx] = f2h(v);
    }
}

// -------- gemm_qkv: MFMA f16, Xh(chunk x 768) @ W(768 x 2304) -> Q,K,V f32
__global__ __launch_bounds__(256, 2) void gemm_qkv(const u16* __restrict__ Xh,
                                                   const u16* __restrict__ Wt,
                                                   const float* __restrict__ bq,
                                                   const float* __restrict__ bv,
                                                   float* __restrict__ Q,
                                                   float* __restrict__ K,
                                                   float* __restrict__ V,
                                                   int b0, int nTok) {
    __shared__ u16 As[128][72];
    __shared__ u16 Bs[128][72];
    int tid = threadIdx.x;
    int t0 = blockIdx.x * 128;
    int n0 = blockIdx.y * 128;
    int lane = tid & 63, w = tid >> 6;
    int wr = (w >> 1) * 64, wc = (w & 1) * 64;
    int lm = lane & 15, lq = lane >> 4;
    int srow = tid >> 3;
    int svec = (tid & 7) * 8;
    const u16* Xb = Xh + (size_t)b0 * S_TOT * 768;

    f32x4 acc[4][4];
#pragma unroll
    for (int mi = 0; mi < 4; mi++)
#pragma unroll
        for (int ni = 0; ni < 4; ni++)
            acc[mi][ni] = (f32x4){0.f, 0.f, 0.f, 0.f};

    for (int k0 = 0; k0 < 768; k0 += 64) {
#pragma unroll
        for (int g = 0; g < 4; g++) {
            int r = srow + g * 32;
            int t = t0 + r;
            uint4 av = make_uint4(0u, 0u, 0u, 0u);
            if (t < nTok) av = *(const uint4*)(Xb + (size_t)t * 768 + k0 + svec);
            *(uint4*)&As[r][svec] = av;
            *(uint4*)&Bs[r][svec] = *(const uint4*)(Wt + (n0 + r) * 768 + k0 + svec);
        }
        __syncthreads();
#pragma unroll
        for (int ks = 0; ks < 64; ks += 32) {
            f16x8 aa[4], bb[4];
#pragma unroll
            for (int mi = 0; mi < 4; mi++)
                aa[mi] = *(const f16x8*)&As[wr + mi * 16 + lm][ks + lq * 8];
#pragma unroll
            for (int ni = 0; ni < 4; ni++)
                bb[ni] = *(const f16x8*)&Bs[wc + ni * 16 + lm][ks + lq * 8];
#pragma unroll
            for (int mi = 0; mi < 4; mi++)
#pragma unroll
                for (int ni = 0; ni < 4; ni++)
                    acc[mi][ni] = __builtin_amdgcn_mfma_f32_16x16x32_f16(aa[mi], bb[ni], acc[mi][ni], 0, 0, 0);
        }
        __syncthreads();
    }

#pragma unroll
    for (int mi = 0; mi < 4; mi++) {
#pragma unroll
        for (int ni = 0; ni < 4; ni++) {
            int n = n0 + wc + ni * 16 + lm;
#pragma unroll
            for (int r = 0; r < 4; r++) {
                int t = t0 + wr + mi * 16 + lq * 4 + r;
                if (t >= nTok) continue;
                float val = acc[mi][ni][r];
                float* dst;
                int nn;
                if (n < 768)       { dst = Q; nn = n;        val += bq[nn]; }
                else if (n < 1536) { dst = K; nn = n - 768;                 }
                else               { dst = V; nn = n - 1536; val += bv[nn]; }
                int bl = t / S_TOT;
                int s = t - bl * S_TOT;
                int h = nn >> 6, d = nn & 63;
                dst[((bl * 12 + h) * S_TOT + s) * 64 + d] = val;
            }
        }
    }
}

// -------- shared f32 64x64 tile compute, then check or repair
static __device__ __forceinline__ void tile64_compute(const float* __restrict__ Xb,
                                                      const float* __restrict__ Wtf,
                                                      int t0, int n0, int nTok,
                                                      float (*Xs)[72], float (*Ws)[72],
                                                      float acc[4][4]) {
    int tid = threadIdx.x;
    int ty = tid >> 4, tx = tid & 15;
    int sr = tid >> 2;
    int sc = (tid & 3) * 4;
#pragma unroll
    for (int ii = 0; ii < 4; ii++)
#pragma unroll
        for (int jj = 0; jj < 4; jj++) acc[ii][jj] = 0.f;

    for (int k0 = 0; k0 < 768; k0 += 64) {
#pragma unroll
        for (int i = 0; i < 4; i++) {
            int c4 = sc + i;
            float4 xv = make_float4(0.f, 0.f, 0.f, 0.f);
            if (t0 + sr < nTok)
                xv = *(const float4*)(Xb + (size_t)(t0 + sr) * 768 + k0 + c4 * 4);
            *(float4*)&Xs[sr][c4 * 4] = xv;
            *(float4*)&Ws[sr][c4 * 4] = *(const float4*)(Wtf + (size_t)(n0 + sr) * 768 + k0 + c4 * 4);
        }
        __syncthreads();
#pragma unroll
        for (int kk = 0; kk < 64; kk += 4) {
            float4 xa[4], wb[4];
#pragma unroll
            for (int ii = 0; ii < 4; ii++) xa[ii] = *(const float4*)&Xs[ty * 4 + ii][kk];
#pragma unroll
            for (int jj = 0; jj < 4; jj++) wb[jj] = *(const float4*)&Ws[tx * 4 + jj][kk];
#pragma unroll
            for (int ii = 0; ii < 4; ii++)
#pragma unroll
                for (int jj = 0; jj < 4; jj++) {
                    acc[ii][jj] = fmaf(xa[ii].x, wb[jj].x, acc[ii][jj]);
                    acc[ii][jj] = fmaf(xa[ii].y, wb[jj].y, acc[ii][jj]);
                    acc[ii][jj] = fmaf(xa[ii].z, wb[jj].z, acc[ii][jj]);
                    acc[ii][jj] = fmaf(xa[ii].w, wb[jj].w, acc[ii][jj]);
                }
        }
        __syncthreads();
    }
}

static __device__ __forceinline__ int qkv_index(int n, int t, float* Q, float* K, float* V,
                                                const float* bq, const float* bv,
                                                float** dstOut, float* biasOut) {
    float* dst; int nn; float bias = 0.f;
    if (n < 768)       { dst = Q; nn = n;        bias = bq[nn]; }
    else if (n < 1536) { dst = K; nn = n - 768;                 }
    else               { dst = V; nn = n - 1536; bias = bv[nn]; }
    int bl = t / S_TOT;
    int s = t - bl * S_TOT;
    *dstOut = dst; *biasOut = bias;
    return ((bl * 12 + (nn >> 6)) * S_TOT + s) * 64 + (nn & 63);
}

// -------- check_gemm: recompute 6 slabs x 64 tokens in f32, compare vs MFMA output
__global__ __launch_bounds__(256) void check_gemm(const float* __restrict__ hs,
                                                  const float* __restrict__ Wtf,
                                                  const float* __restrict__ bq,
                                                  const float* __restrict__ bv,
                                                  float* __restrict__ Q,
                                                  float* __restrict__ K,
                                                  float* __restrict__ V,
                                                  int b0, int nTok,
                                                  int* __restrict__ flag) {
    __shared__ float Xs[64][72];
    __shared__ float Ws[64][72];
    int si = blockIdx.x;
    int t0;
    if (si < 2)      t0 = si * 64;
    else if (si < 4) t0 = ((nTok / 2 - 64) & ~63) + (si - 2) * 64;
    else             t0 = nTok - 128 + (si - 4) * 64;
    int n0 = blockIdx.y * 64;
    const float* Xb = hs + (size_t)b0 * S_TOT * 768;
    float acc[4][4];
    tile64_compute(Xb, Wtf, t0, n0, nTok, Xs, Ws, acc);

    int ty = threadIdx.x >> 4, tx = threadIdx.x & 15;
    int bad = 0;
#pragma unroll
    for (int ii = 0; ii < 4; ii++) {
#pragma unroll
        for (int jj = 0; jj < 4; jj++) {
            int t = t0 + ty * 4 + ii;
            int n = n0 + tx * 4 + jj;
            float* dst; float bias;
            int idx = qkv_index(n, t, Q, K, V, bq, bv, &dst, &bias);
            float expect = acc[ii][jj] + bias;
            if (fabsf(expect - dst[idx]) > 8e-3f) bad = 1;
        }
    }
    if (bad) atomicOr(flag, 1);
}

// -------- repair_gemm: full f32 tiled GEMM, early-exit if check passed
__global__ __launch_bounds__(256) void repair_gemm(const float* __restrict__ hs,
                                                   const float* __restrict__ Wtf,
                                                   const float* __restrict__ bq,
                                                   const float* __restrict__ bv,
                                                   float* __restrict__ Q,
                                                   float* __restrict__ K,
                                                   float* __restrict__ V,
                                                   int b0, int nTok,
                                                   const int* __restrict__ flag) {
    if (*flag == 0) return;
    __shared__ float Xs[64][72];
    __shared__ float Ws[64][72];
    int t0 = blockIdx.x * 64;
    int n0 = blockIdx.y * 64;
    const float* Xb = hs + (size_t)b0 * S_TOT * 768;
    float acc[4][4];
    tile64_compute(Xb, Wtf, t0, n0, nTok, Xs, Ws, acc);

    int ty = threadIdx.x >> 4, tx = threadIdx.x & 15;
#pragma unroll
    for (int ii = 0; ii < 4; ii++) {
#pragma unroll
        for (int jj = 0; jj < 4; jj++) {
            int t = t0 + ty * 4 + ii;
            if (t >= nTok) continue;
            int n = n0 + tx * 4 + jj;
            float* dst; float bias;
            int idx = qkv_index(n, t, Q, K, V, bq, bv, &dst, &bias);
            dst[idx] = acc[ii][jj] + bias;
        }
    }
}

// -------- cls attention (R7 verbatim)
__global__ __launch_bounds__(256) void cls_attn(const float* __restrict__ Q,
                                                const float* __restrict__ K,
                                                const float* __restrict__ V,
                                                const float* __restrict__ rel,
                                                const int* __restrict__ rpi,
                                                float* __restrict__ out, int b0) {
    int bh = blockIdx.x;
    int bl = bh / 12, h = bh - bl * 12;
    __shared__ float p[S_TOT];
    __shared__ float4 qs4[16];
    __shared__ float red[256];
    __shared__ float wred[8];
    int tid = threadIdx.x, lane = tid & 63, w = tid >> 6;
    size_t base = (size_t)bh * S_TOT * 64;
    const float* Qb = Q + base;
    const float* Kb = K + base;
    const float* Vb = V + base;
    if (tid < 64) ((float*)qs4)[tid] = Qb[tid];
    __syncthreads();

    float lmx = -1e30f;
    for (int j = tid; j < S_TOT; j += 256) {
        const float4* kr = (const float4*)(Kb + j * 64);
        float a = 0.f;
#pragma unroll
        for (int d4 = 0; d4 < 16; d4++) {
            float4 kv = kr[d4];
            float4 qv = qs4[d4];
            a = fmaf(qv.x, kv.x, a); a = fmaf(qv.y, kv.y, a);
            a = fmaf(qv.z, kv.z, a); a = fmaf(qv.w, kv.w, a);
        }
        a = a * 0.125f + rel[rpi[j] * 12 + h];
        p[j] = a;
        lmx = fmaxf(lmx, a);
    }
#pragma unroll
    for (int off = 32; off > 0; off >>= 1) lmx = fmaxf(lmx, __shfl_xor(lmx, off));
    if (lane == 0) wred[w] = lmx;
    __syncthreads();
    float mx = fmaxf(fmaxf(wred[0], wred[1]), fmaxf(wred[2], wred[3]));
    float lsum = 0.f;
    for (int j = tid; j < S_TOT; j += 256) {
        float e = __expf(p[j] - mx);
        p[j] = e;
        lsum += e;
    }
#pragma unroll
    for (int off = 32; off > 0; off >>= 1) lsum += __shfl_xor(lsum, off);
    if (lane == 0) wred[4 + w] = lsum;
    __syncthreads();
    float inv = 1.0f / (wred[4] + wred[5] + wred[6] + wred[7]);
    float acc = 0.f;
    for (int j = w; j < S_TOT; j += 4) acc = fmaf(p[j], Vb[j * 64 + lane], acc);
    red[w * 64 + lane] = acc;
    __syncthreads();
    if (w == 0) {
        float o = (red[lane] + red[64 + lane] + red[128 + lane] + red[192 + lane]) * inv;
        out[(size_t)(b0 + bl) * S_TOT * 768 + h * 64 + lane] = o;
    }
}

// -------- block-sparse local attention (R7 verbatim)
__global__ __launch_bounds__(256) void loc_attn(const float* __restrict__ Q,
                                                const float* __restrict__ K,
                                                const float* __restrict__ V,
                                                const float* __restrict__ rel,
                                                const int* __restrict__ rpi,
                                                const int* __restrict__ rand_idx,
                                                float* __restrict__ out, int b0) {
    int m = blockIdx.x;
    int h = blockIdx.y;
    int bl = blockIdx.z;
    __shared__ float sim[52 * 295];
    __shared__ int   tok[295];
    __shared__ float rs[49];
    int tid = threadIdx.x, lane = tid & 63, w = tid >> 6;
    int nrows = (w == 0) ? 13 : 12;

    for (int jj = tid; jj < 295; jj += 256) {
        int t;
        if (jj == 0) t = 0;
        else {
            int j1 = jj - 1;
            int n = j1 / 49;
            int q = j1 - n * 49;
            int a;
            if (n == 0)      a = (m + 31) & 31;
            else if (n == 1) a = m;
            else if (n == 2) a = (m + 1) & 31;
            else             a = rand_idx[m * 3 + (n - 3)];
            t = 1 + a * 49 + q;
        }
        tok[jj] = t;
    }
    for (int z = tid; z < 3 * 295; z += 256) sim[49 * 295 + z] = 0.f;
    __syncthreads();

    size_t base = (size_t)((bl * 12 + h) * S_TOT) * 64;
    const float* Qb = Q + base;
    const float* Kb = K + base;
    const float* Vb = V + base;

    for (int jc = 0; jc < 5; jc++) {
        int j = jc * 64 + lane;
        bool jv = j < 295;
        int tj = jv ? tok[j] : 0;
        const float4* krow = (const float4*)(Kb + tj * 64);
        float4 kf[16];
#pragma unroll
        for (int d4 = 0; d4 < 16; d4++) kf[d4] = krow[d4];
        for (int r = 0; r < nrows; r++) {
            int i = w + 4 * r;
            int qr = 1 + m * 49 + i;
            const float4* qrow = (const float4*)(Qb + qr * 64);
            float a = 0.f;
#pragma unroll
            for (int d4 = 0; d4 < 16; d4++) {
                float4 qv = qrow[d4];
                float4 kv = kf[d4];
                a = fmaf(qv.x, kv.x, a); a = fmaf(qv.y, kv.y, a);
                a = fmaf(qv.z, kv.z, a); a = fmaf(qv.w, kv.w, a);
            }
            if (jv) {
                float sv = a * 0.125f + rel[rpi[qr * S_TOT + tj] * 12 + h];
                sim[i * 295 + j] = sv;
            }
        }
    }
    __syncthreads();

    for (int r = 0; r < nrows; r++) {
        int i = w + 4 * r;
        float mx = -1e30f;
#pragma unroll
        for (int jc = 0; jc < 5; jc++) {
            int j = jc * 64 + lane;
            if (j < 295) mx = fmaxf(mx, sim[i * 295 + j]);
        }
#pragma unroll
        for (int off = 32; off > 0; off >>= 1) mx = fmaxf(mx, __shfl_xor(mx, off));
        float sum = 0.f;
#pragma unroll
        for (int jc = 0; jc < 5; jc++) {
            int j = jc * 64 + lane;
            if (j < 295) {
                float e = __expf(sim[i * 295 + j] - mx);
                sim[i * 295 + j] = e;
                sum += e;
            }
        }
#pragma unroll
        for (int off = 32; off > 0; off >>= 1) sum += __shfl_xor(sum, off);
        if (lane == 0) rs[i] = 1.0f / sum;
    }
    __syncthreads();

    float facc[13];
#pragma unroll
    for (int r = 0; r < 13; r++) facc[r] = 0.f;
    for (int j = 0; j < 295; j++) {
        float vv = Vb[tok[j] * 64 + lane];
#pragma unroll
        for (int r = 0; r < 13; r++)
            facc[r] = fmaf(sim[(w + 4 * r) * 295 + j], vv, facc[r]);
    }
    for (int r = 0; r < nrows; r++) {
        int i = w + 4 * r;
        int s = 1 + m * 49 + i;
        out[((size_t)(b0 + bl) * S_TOT + s) * 768 + h * 64 + lane] = facc[r] * rs[i];
    }
}

extern "C" void kernel_launch(void* const* d_in, const int* in_sizes, int n_in,
                              void* d_out, int out_size, void* d_ws, size_t ws_size,
                              hipStream_t stream) {
    (void)in_sizes; (void)n_in; (void)out_size;
    const float* hs  = (const float*)d_in[0];
    const float* Wq  = (const float*)d_in[1];
    const float* bq  = (const float*)d_in[2];
    const float* Wk  = (const float*)d_in[3];
    const float* Wv  = (const float*)d_in[4];
    const float* bv  = (const float*)d_in[5];
    const float* rel = (const float*)d_in[6];
    const int*   rpi = (const int*)d_in[7];
    const int*   rnd = (const int*)d_in[8];
    float* out = (float*)d_out;
    char* ws = (char*)d_ws;

    // ws layout: flag | Xh f16 | Wt f16 | Wtf f32 | QKV f32
    constexpr size_t FLAG_OFF = 0;
    constexpr size_t XH_OFF   = 64;
    constexpr size_t WT_OFF   = XH_OFF + (size_t)NX * 2;             // 19,275,328
    constexpr size_t WTF_OFF  = WT_OFF + (size_t)NCOL * 768 * 2;     // 22,814,272
    constexpr size_t QKV_OFF  = WTF_OFF + (size_t)NCOL * 768 * 4;    // 29,892,160
    constexpr size_t PBUF     = (size_t)12 * S_TOT * 64 * 4;         //  4,819,968

    int*   flag = (int*)(ws + FLAG_OFF);
    u16*   Xh   = (u16*)(ws + XH_OFF);
    u16*   Wt   = (u16*)(ws + WT_OFF);
    float* Wtf  = (float*)(ws + WTF_OFF);

    int C = 1;
    if (ws_size > QKV_OFF + 3 * PBUF) {
        size_t c = (ws_size - QKV_OFF) / (3 * PBUF);
        C = (c >= NBATCH) ? NBATCH : (int)c;
        if (C < 1) C = 1;
    }
    float* Q = (float*)(ws + QKV_OFF);
    float* K = (float*)(ws + QKV_OFF + (size_t)C * PBUF);
    float* V = (float*)(ws + QKV_OFF + (size_t)C * PBUF * 2);

    init_flag<<<dim3(1), dim3(1), 0, stream>>>(flag);
    conv_x<<<dim3((NX / 8 + 255) / 256), dim3(256), 0, stream>>>(hs, Xh);
    conv_w2<<<dim3(72, 24), dim3(256), 0, stream>>>(Wq, Wk, Wv, Wtf, Wt);

    for (int b0 = 0; b0 < NBATCH; b0 += C) {
        int cb = (NBATCH - b0 < C) ? (NBATCH - b0) : C;
        int nTok = cb * S_TOT;
        gemm_qkv<<<dim3((nTok + 127) / 128, NCOL / 128), dim3(256), 0, stream>>>(
            Xh, Wt, bq, bv, Q, K, V, b0, nTok);
        check_gemm<<<dim3(6, NCOL / 64), dim3(256), 0, stream>>>(
            hs, Wtf, bq, bv, Q, K, V, b0, nTok, flag);
        repair_gemm<<<dim3((nTok + 63) / 64, NCOL / 64), dim3(256), 0, stream>>>(
            hs, Wtf, bq, bv, Q, K, V, b0, nTok, flag);
        cls_attn<<<dim3(12 * cb), dim3(256), 0, stream>>>(Q, K, V, rel, rpi, out, b0);
        loc_attn<<<dim3(32, 12, cb), dim3(256), 0, stream>>>(Q, K, V, rel, rpi, rnd, out, b0);
    }
}

// Round 9
// 2007.344 us; speedup vs baseline: 5.0751x; 1.5724x over previous
//
#include <hip/hip_runtime.h>
#include <hip/hip_bf16.h>

// BeitSelfAttention — verified-bf16 MFMA GEMM with split-X precision recovery.
// X = Xhi + Xlo (both bf16, exact split); W single-rounded bf16.
// C = Xhi*W + Xlo*W via mfma_f32_16x16x32_bf16 (the m92/m97 HW-verified pattern).
// check_gemm (f32 recompute of 6 slabs) + repair_gemm (early-exit) kept as safety net.
// Attention kernels verbatim from passing rounds 7/8.
// Shapes: B=8 S=1569 D=768 NH=12 DH=64 NCLS=1 BS=49 M=32 NKV=6

#define S_TOT   1569
#define NCOL    2304          // 3*768
#define NBATCH  8
#define NX      9637632       // 8*1569*768

typedef __attribute__((ext_vector_type(8))) short bf16x8;   // 8 bf16 (4 VGPRs)
typedef __attribute__((ext_vector_type(4))) float f32x4;
typedef unsigned short u16;

static __device__ __forceinline__ u16 f2bf(float x) {
    __hip_bfloat16 b = __float2bfloat16(x);
    return *reinterpret_cast<u16*>(&b);
}
static __device__ __forceinline__ float bf2f(u16 u) {
    __hip_bfloat16 b;
    *reinterpret_cast<u16*>(&b) = u;
    return __bfloat162float(b);
}

__global__ void init_flag(int* flag) { *flag = 0; }

// -------- conv_x: hs f32 -> Xhi = bf16(x), Xlo = bf16(x - Xhi)
__global__ __launch_bounds__(256) void conv_x(const float* __restrict__ hs,
                                              u16* __restrict__ Xhi,
                                              u16* __restrict__ Xlo) {
    int v = blockIdx.x * 256 + threadIdx.x;     // 8-element group index
    if (v >= NX / 8) return;
    const float4* src = (const float4*)hs + 2 * (size_t)v;
    float4 x0 = src[0], x1 = src[1];
    float xs[8] = {x0.x, x0.y, x0.z, x0.w, x1.x, x1.y, x1.z, x1.w};
    u16 hi[8], lo[8];
#pragma unroll
    for (int i = 0; i < 8; i++) {
        u16 hb = f2bf(xs[i]);
        hi[i] = hb;
        lo[i] = f2bf(xs[i] - bf2f(hb));
    }
    uint4 hv, lv;
    hv.x = hi[0] | ((unsigned)hi[1] << 16);  hv.y = hi[2] | ((unsigned)hi[3] << 16);
    hv.z = hi[4] | ((unsigned)hi[5] << 16);  hv.w = hi[6] | ((unsigned)hi[7] << 16);
    lv.x = lo[0] | ((unsigned)lo[1] << 16);  lv.y = lo[2] | ((unsigned)lo[3] << 16);
    lv.z = lo[4] | ((unsigned)lo[5] << 16);  lv.w = lo[6] | ((unsigned)lo[7] << 16);
    ((uint4*)Xhi)[v] = hv;
    ((uint4*)Xlo)[v] = lv;
}

// -------- conv_w2: W (768x768 f32 x3) -> Wtf f32 (2304x768, W^T) AND Wt bf16
__global__ __launch_bounds__(256) void conv_w2(const float* __restrict__ Wq,
                                               const float* __restrict__ Wk,
                                               const float* __restrict__ Wv,
                                               float* __restrict__ Wtf,
                                               u16* __restrict__ Wt) {
    __shared__ float tile[32][33];
    int n0 = blockIdx.x * 32;
    int d0 = blockIdx.y * 32;
    int tx = threadIdx.x & 31, ty = threadIdx.x >> 5;
    int which = n0 / 768;
    int nn0 = n0 - which * 768;
    const float* W = (which == 0) ? Wq : (which == 1 ? Wk : Wv);
#pragma unroll
    for (int k = 0; k < 4; k++)
        tile[ty + 8 * k][tx] = W[(d0 + ty + 8 * k) * 768 + nn0 + tx];
    __syncthreads();
#pragma unroll
    for (int k = 0; k < 4; k++) {
        float v = tile[tx][ty + 8 * k];
        int idx = (n0 + ty + 8 * k) * 768 + d0 + tx;
        Wtf[idx] = v;
        Wt[idx] = f2bf(v);
    }
}

// -------- gemm_qkv: (Xhi+Xlo)(chunk x 768 bf16) @ W(768 x 2304 bf16) -> Q,K,V f32
__global__ __launch_bounds__(256, 2) void gemm_qkv(const u16* __restrict__ Xhi,
                                                   const u16* __restrict__ Xlo,
                                                   const u16* __restrict__ Wt,
                                                   const float* __restrict__ bq,
                                                   const float* __restrict__ bv,
                                                   float* __restrict__ Q,
                                                   float* __restrict__ K,
                                                   float* __restrict__ V,
                                                   int b0, int nTok) {
    __shared__ u16 Ah[128][72];
    __shared__ u16 Al[128][72];
    __shared__ u16 Bs[128][72];
    int tid = threadIdx.x;
    int t0 = blockIdx.x * 128;
    int n0 = blockIdx.y * 128;
    int lane = tid & 63, w = tid >> 6;
    int wr = (w >> 1) * 64, wc = (w & 1) * 64;
    int lm = lane & 15, lq = lane >> 4;
    int srow = tid >> 3;
    int svec = (tid & 7) * 8;
    const u16* Xhb = Xhi + (size_t)b0 * S_TOT * 768;
    const u16* Xlb = Xlo + (size_t)b0 * S_TOT * 768;

    f32x4 acc[4][4];
#pragma unroll
    for (int mi = 0; mi < 4; mi++)
#pragma unroll
        for (int ni = 0; ni < 4; ni++)
            acc[mi][ni] = (f32x4){0.f, 0.f, 0.f, 0.f};

    for (int k0 = 0; k0 < 768; k0 += 64) {
#pragma unroll
        for (int g = 0; g < 4; g++) {
            int r = srow + g * 32;
            int t = t0 + r;
            uint4 hv = make_uint4(0u, 0u, 0u, 0u);
            uint4 lv = make_uint4(0u, 0u, 0u, 0u);
            if (t < nTok) {
                hv = *(const uint4*)(Xhb + (size_t)t * 768 + k0 + svec);
                lv = *(const uint4*)(Xlb + (size_t)t * 768 + k0 + svec);
            }
            *(uint4*)&Ah[r][svec] = hv;
            *(uint4*)&Al[r][svec] = lv;
            *(uint4*)&Bs[r][svec] = *(const uint4*)(Wt + (n0 + r) * 768 + k0 + svec);
        }
        __syncthreads();
#pragma unroll
        for (int ks = 0; ks < 64; ks += 32) {
            bf16x8 ah[4], al[4], bb[4];
#pragma unroll
            for (int mi = 0; mi < 4; mi++) {
                ah[mi] = *(const bf16x8*)&Ah[wr + mi * 16 + lm][ks + lq * 8];
                al[mi] = *(const bf16x8*)&Al[wr + mi * 16 + lm][ks + lq * 8];
            }
#pragma unroll
            for (int ni = 0; ni < 4; ni++)
                bb[ni] = *(const bf16x8*)&Bs[wc + ni * 16 + lm][ks + lq * 8];
#pragma unroll
            for (int mi = 0; mi < 4; mi++)
#pragma unroll
                for (int ni = 0; ni < 4; ni++) {
                    acc[mi][ni] = __builtin_amdgcn_mfma_f32_16x16x32_bf16(ah[mi], bb[ni], acc[mi][ni], 0, 0, 0);
                    acc[mi][ni] = __builtin_amdgcn_mfma_f32_16x16x32_bf16(al[mi], bb[ni], acc[mi][ni], 0, 0, 0);
                }
        }
        __syncthreads();
    }

    // epilogue: D[row=(lane>>4)*4+r][col=lane&15]  (m89/m91-verified)
#pragma unroll
    for (int mi = 0; mi < 4; mi++) {
#pragma unroll
        for (int ni = 0; ni < 4; ni++) {
            int n = n0 + wc + ni * 16 + lm;
#pragma unroll
            for (int r = 0; r < 4; r++) {
                int t = t0 + wr + mi * 16 + lq * 4 + r;
                if (t >= nTok) continue;
                float val = acc[mi][ni][r];
                float* dst;
                int nn;
                if (n < 768)       { dst = Q; nn = n;        val += bq[nn]; }
                else if (n < 1536) { dst = K; nn = n - 768;                 }
                else               { dst = V; nn = n - 1536; val += bv[nn]; }
                int bl = t / S_TOT;
                int s = t - bl * S_TOT;
                int h = nn >> 6, d = nn & 63;
                dst[((bl * 12 + h) * S_TOT + s) * 64 + d] = val;
            }
        }
    }
}

// -------- shared f32 64x64 tile compute (XOR-swizzled LDS: kills 16-way conflicts)
static __device__ __forceinline__ void tile64_compute(const float* __restrict__ Xb,
                                                      const float* __restrict__ Wtf,
                                                      int t0, int n0, int nTok,
                                                      float (*Xs)[72], float (*Ws)[72],
                                                      float acc[4][4]) {
    int tid = threadIdx.x;
    int ty = tid >> 4, tx = tid & 15;
    int sr = tid >> 2;
    int sc = (tid & 3) * 4;
#pragma unroll
    for (int ii = 0; ii < 4; ii++)
#pragma unroll
        for (int jj = 0; jj < 4; jj++) acc[ii][jj] = 0.f;

    for (int k0 = 0; k0 < 768; k0 += 64) {
#pragma unroll
        for (int i = 0; i < 4; i++) {
            int c4 = sc + i;                     // logical col-group 0..15
            int c4s = c4 ^ (sr >> 2);            // swizzled store col-group
            float4 xv = make_float4(0.f, 0.f, 0.f, 0.f);
            if (t0 + sr < nTok)
                xv = *(const float4*)(Xb + (size_t)(t0 + sr) * 768 + k0 + c4 * 4);
            *(float4*)&Xs[sr][c4s * 4] = xv;
            *(float4*)&Ws[sr][c4s * 4] = *(const float4*)(Wtf + (size_t)(n0 + sr) * 768 + k0 + c4 * 4);
        }
        __syncthreads();
#pragma unroll
        for (int k4 = 0; k4 < 16; k4++) {
            float4 xa[4], wb[4];
#pragma unroll
            for (int ii = 0; ii < 4; ii++) {
                int R = ty * 4 + ii;
                xa[ii] = *(const float4*)&Xs[R][(k4 ^ (R >> 2)) * 4];
            }
#pragma unroll
            for (int jj = 0; jj < 4; jj++) {
                int R = tx * 4 + jj;
                wb[jj] = *(const float4*)&Ws[R][(k4 ^ (R >> 2)) * 4];
            }
#pragma unroll
            for (int ii = 0; ii < 4; ii++)
#pragma unroll
                for (int jj = 0; jj < 4; jj++) {
                    acc[ii][jj] = fmaf(xa[ii].x, wb[jj].x, acc[ii][jj]);
                    acc[ii][jj] = fmaf(xa[ii].y, wb[jj].y, acc[ii][jj]);
                    acc[ii][jj] = fmaf(xa[ii].z, wb[jj].z, acc[ii][jj]);
                    acc[ii][jj] = fmaf(xa[ii].w, wb[jj].w, acc[ii][jj]);
                }
        }
        __syncthreads();
    }
}

static __device__ __forceinline__ int qkv_index(int n, int t, float* Q, float* K, float* V,
                                                const float* bq, const float* bv,
                                                float** dstOut, float* biasOut) {
    float* dst; int nn; float bias = 0.f;
    if (n < 768)       { dst = Q; nn = n;        bias = bq[nn]; }
    else if (n < 1536) { dst = K; nn = n - 768;                 }
    else               { dst = V; nn = n - 1536; bias = bv[nn]; }
    int bl = t / S_TOT;
    int s = t - bl * S_TOT;
    *dstOut = dst; *biasOut = bias;
    return ((bl * 12 + (nn >> 6)) * S_TOT + s) * 64 + (nn & 63);
}

// -------- check_gemm: recompute 6 slabs x 64 tokens in f32, compare vs MFMA output
__global__ __launch_bounds__(256) void check_gemm(const float* __restrict__ hs,
                                                  const float* __restrict__ Wtf,
                                                  const float* __restrict__ bq,
                                                  const float* __restrict__ bv,
                                                  float* __restrict__ Q,
                                                  float* __restrict__ K,
                                                  float* __restrict__ V,
                                                  int b0, int nTok,
                                                  int* __restrict__ flag) {
    __shared__ float Xs[64][72];
    __shared__ float Ws[64][72];
    int si = blockIdx.x;
    int t0;
    if (si < 2)      t0 = si * 64;
    else if (si < 4) t0 = ((nTok / 2 - 64) & ~63) + (si - 2) * 64;
    else             t0 = nTok - 128 + (si - 4) * 64;
    int n0 = blockIdx.y * 64;
    const float* Xb = hs + (size_t)b0 * S_TOT * 768;
    float acc[4][4];
    tile64_compute(Xb, Wtf, t0, n0, nTok, Xs, Ws, acc);

    int ty = threadIdx.x >> 4, tx = threadIdx.x & 15;
    int bad = 0;
#pragma unroll
    for (int ii = 0; ii < 4; ii++) {
#pragma unroll
        for (int jj = 0; jj < 4; jj++) {
            int t = t0 + ty * 4 + ii;
            int n = n0 + tx * 4 + jj;
            float* dst; float bias;
            int idx = qkv_index(n, t, Q, K, V, bq, bv, &dst, &bias);
            float expect = acc[ii][jj] + bias;
            if (fabsf(expect - dst[idx]) > 1e-2f) bad = 1;   // split-bf16 noise max ~6.5e-3
        }
    }
    if (bad) atomicOr(flag, 1);
}

// -------- repair_gemm: full f32 tiled GEMM, early-exit if check passed
__global__ __launch_bounds__(256) void repair_gemm(const float* __restrict__ hs,
                                                   const float* __restrict__ Wtf,
                                                   const float* __restrict__ bq,
                                                   const float* __restrict__ bv,
                                                   float* __restrict__ Q,
                                                   float* __restrict__ K,
                                                   float* __restrict__ V,
                                                   int b0, int nTok,
                                                   const int* __restrict__ flag) {
    if (*flag == 0) return;
    __shared__ float Xs[64][72];
    __shared__ float Ws[64][72];
    int t0 = blockIdx.x * 64;
    int n0 = blockIdx.y * 64;
    const float* Xb = hs + (size_t)b0 * S_TOT * 768;
    float acc[4][4];
    tile64_compute(Xb, Wtf, t0, n0, nTok, Xs, Ws, acc);

    int ty = threadIdx.x >> 4, tx = threadIdx.x & 15;
#pragma unroll
    for (int ii = 0; ii < 4; ii++) {
#pragma unroll
        for (int jj = 0; jj < 4; jj++) {
            int t = t0 + ty * 4 + ii;
            if (t >= nTok) continue;
            int n = n0 + tx * 4 + jj;
            float* dst; float bias;
            int idx = qkv_index(n, t, Q, K, V, bq, bv, &dst, &bias);
            dst[idx] = acc[ii][jj] + bias;
        }
    }
}

// -------- cls attention (R7 verbatim)
__global__ __launch_bounds__(256) void cls_attn(const float* __restrict__ Q,
                                                const float* __restrict__ K,
                                                const float* __restrict__ V,
                                                const float* __restrict__ rel,
                                                const int* __restrict__ rpi,
                                                float* __restrict__ out, int b0) {
    int bh = blockIdx.x;
    int bl = bh / 12, h = bh - bl * 12;
    __shared__ float p[S_TOT];
    __shared__ float4 qs4[16];
    __shared__ float red[256];
    __shared__ float wred[8];
    int tid = threadIdx.x, lane = tid & 63, w = tid >> 6;
    size_t base = (size_t)bh * S_TOT * 64;
    const float* Qb = Q + base;
    const float* Kb = K + base;
    const float* Vb = V + base;
    if (tid < 64) ((float*)qs4)[tid] = Qb[tid];
    __syncthreads();

    float lmx = -1e30f;
    for (int j = tid; j < S_TOT; j += 256) {
        const float4* kr = (const float4*)(Kb + j * 64);
        float a = 0.f;
#pragma unroll
        for (int d4 = 0; d4 < 16; d4++) {
            float4 kv = kr[d4];
            float4 qv = qs4[d4];
            a = fmaf(qv.x, kv.x, a); a = fmaf(qv.y, kv.y, a);
            a = fmaf(qv.z, kv.z, a); a = fmaf(qv.w, kv.w, a);
        }
        a = a * 0.125f + rel[rpi[j] * 12 + h];
        p[j] = a;
        lmx = fmaxf(lmx, a);
    }
#pragma unroll
    for (int off = 32; off > 0; off >>= 1) lmx = fmaxf(lmx, __shfl_xor(lmx, off));
    if (lane == 0) wred[w] = lmx;
    __syncthreads();
    float mx = fmaxf(fmaxf(wred[0], wred[1]), fmaxf(wred[2], wred[3]));
    float lsum = 0.f;
    for (int j = tid; j < S_TOT; j += 256) {
        float e = __expf(p[j] - mx);
        p[j] = e;
        lsum += e;
    }
#pragma unroll
    for (int off = 32; off > 0; off >>= 1) lsum += __shfl_xor(lsum, off);
    if (lane == 0) wred[4 + w] = lsum;
    __syncthreads();
    float inv = 1.0f / (wred[4] + wred[5] + wred[6] + wred[7]);
    float acc = 0.f;
    for (int j = w; j < S_TOT; j += 4) acc = fmaf(p[j], Vb[j * 64 + lane], acc);
    red[w * 64 + lane] = acc;
    __syncthreads();
    if (w == 0) {
        float o = (red[lane] + red[64 + lane] + red[128 + lane] + red[192 + lane]) * inv;
        out[(size_t)(b0 + bl) * S_TOT * 768 + h * 64 + lane] = o;
    }
}

// -------- block-sparse local attention (R7 verbatim)
__global__ __launch_bounds__(256) void loc_attn(const float* __restrict__ Q,
                                                const float* __restrict__ K,
                                                const float* __restrict__ V,
                                                const float* __restrict__ rel,
                                                const int* __restrict__ rpi,
                                                const int* __restrict__ rand_idx,
                                                float* __restrict__ out, int b0) {
    int m = blockIdx.x;
    int h = blockIdx.y;
    int bl = blockIdx.z;
    __shared__ float sim[52 * 295];
    __shared__ int   tok[295];
    __shared__ float rs[49];
    int tid = threadIdx.x, lane = tid & 63, w = tid >> 6;
    int nrows = (w == 0) ? 13 : 12;

    for (int jj = tid; jj < 295; jj += 256) {
        int t;
        if (jj == 0) t = 0;
        else {
            int j1 = jj - 1;
            int n = j1 / 49;
            int q = j1 - n * 49;
            int a;
            if (n == 0)      a = (m + 31) & 31;
            else if (n == 1) a = m;
            else if (n == 2) a = (m + 1) & 31;
            else             a = rand_idx[m * 3 + (n - 3)];
            t = 1 + a * 49 + q;
        }
        tok[jj] = t;
    }
    for (int z = tid; z < 3 * 295; z += 256) sim[49 * 295 + z] = 0.f;
    __syncthreads();

    size_t base = (size_t)((bl * 12 + h) * S_TOT) * 64;
    const float* Qb = Q + base;
    const float* Kb = K + base;
    const float* Vb = V + base;

    for (int jc = 0; jc < 5; jc++) {
        int j = jc * 64 + lane;
        bool jv = j < 295;
        int tj = jv ? tok[j] : 0;
        const float4* krow = (const float4*)(Kb + tj * 64);
        float4 kf[16];
#pragma unroll
        for (int d4 = 0; d4 < 16; d4++) kf[d4] = krow[d4];
        for (int r = 0; r < nrows; r++) {
            int i = w + 4 * r;
            int qr = 1 + m * 49 + i;
            const float4* qrow = (const float4*)(Qb + qr * 64);
            float a = 0.f;
#pragma unroll
            for (int d4 = 0; d4 < 16; d4++) {
                float4 qv = qrow[d4];
                float4 kv = kf[d4];
                a = fmaf(qv.x, kv.x, a); a = fmaf(qv.y, kv.y, a);
                a = fmaf(qv.z, kv.z, a); a = fmaf(qv.w, kv.w, a);
            }
            if (jv) {
                float sv = a * 0.125f + rel[rpi[qr * S_TOT + tj] * 12 + h];
                sim[i * 295 + j] = sv;
            }
        }
    }
    __syncthreads();

    for (int r = 0; r < nrows; r++) {
        int i = w + 4 * r;
        float mx = -1e30f;
#pragma unroll
        for (int jc = 0; jc < 5; jc++) {
            int j = jc * 64 + lane;
            if (j < 295) mx = fmaxf(mx, sim[i * 295 + j]);
        }
#pragma unroll
        for (int off = 32; off > 0; off >>= 1) mx = fmaxf(mx, __shfl_xor(mx, off));
        float sum = 0.f;
#pragma unroll
        for (int jc = 0; jc < 5; jc++) {
            int j = jc * 64 + lane;
            if (j < 295) {
                float e = __expf(sim[i * 295 + j] - mx);
                sim[i * 295 + j] = e;
                sum += e;
            }
        }
#pragma unroll
        for (int off = 32; off > 0; off >>= 1) sum += __shfl_xor(sum, off);
        if (lane == 0) rs[i] = 1.0f / sum;
    }
    __syncthreads();

    float facc[13];
#pragma unroll
    for (int r = 0; r < 13; r++) facc[r] = 0.f;
    for (int j = 0; j < 295; j++) {
        float vv = Vb[tok[j] * 64 + lane];
#pragma unroll
        for (int r = 0; r < 13; r++)
            facc[r] = fmaf(sim[(w + 4 * r) * 295 + j], vv, facc[r]);
    }
    for (int r = 0; r < nrows; r++) {
        int i = w + 4 * r;
        int s = 1 + m * 49 + i;
        out[((size_t)(b0 + bl) * S_TOT + s) * 768 + h * 64 + lane] = facc[r] * rs[i];
    }
}

extern "C" void kernel_launch(void* const* d_in, const int* in_sizes, int n_in,
                              void* d_out, int out_size, void* d_ws, size_t ws_size,
                              hipStream_t stream) {
    (void)in_sizes; (void)n_in; (void)out_size;
    const float* hs  = (const float*)d_in[0];
    const float* Wq  = (const float*)d_in[1];
    const float* bq  = (const float*)d_in[2];
    const float* Wk  = (const float*)d_in[3];
    const float* Wv  = (const float*)d_in[4];
    const float* bv  = (const float*)d_in[5];
    const float* rel = (const float*)d_in[6];
    const int*   rpi = (const int*)d_in[7];
    const int*   rnd = (const int*)d_in[8];
    float* out = (float*)d_out;
    char* ws = (char*)d_ws;

    // ws layout: flag | Xhi bf16 | Xlo bf16 | Wt bf16 | Wtf f32 | QKV f32
    constexpr size_t FLAG_OFF = 0;
    constexpr size_t XHI_OFF  = 64;
    constexpr size_t XLO_OFF  = XHI_OFF + (size_t)NX * 2;            // +19,275,264
    constexpr size_t WT_OFF   = XLO_OFF + (size_t)NX * 2;
    constexpr size_t WTF_OFF  = WT_OFF + (size_t)NCOL * 768 * 2;     // +3,538,944
    constexpr size_t QKV_OFF  = WTF_OFF + (size_t)NCOL * 768 * 4;    // +7,077,888
    constexpr size_t PBUF     = (size_t)12 * S_TOT * 64 * 4;         //  4,819,968

    int*   flag = (int*)(ws + FLAG_OFF);
    u16*   Xhi  = (u16*)(ws + XHI_OFF);
    u16*   Xlo  = (u16*)(ws + XLO_OFF);
    u16*   Wt   = (u16*)(ws + WT_OFF);
    float* Wtf  = (float*)(ws + WTF_OFF);

    int C = 1;
    if (ws_size > QKV_OFF + 3 * PBUF) {
        size_t c = (ws_size - QKV_OFF) / (3 * PBUF);
        C = (c >= NBATCH) ? NBATCH : (int)c;
        if (C < 1) C = 1;
    }
    float* Q = (float*)(ws + QKV_OFF);
    float* K = (float*)(ws + QKV_OFF + (size_t)C * PBUF);
    float* V = (float*)(ws + QKV_OFF + (size_t)C * PBUF * 2);

    init_flag<<<dim3(1), dim3(1), 0, stream>>>(flag);
    conv_x<<<dim3((NX / 8 + 255) / 256), dim3(256), 0, stream>>>(hs, Xhi, Xlo);
    conv_w2<<<dim3(72, 24), dim3(256), 0, stream>>>(Wq, Wk, Wv, Wtf, Wt);

    for (int b0 = 0; b0 < NBATCH; b0 += C) {
        int cb = (NBATCH - b0 < C) ? (NBATCH - b0) : C;
        int nTok = cb * S_TOT;
        gemm_qkv<<<dim3((nTok + 127) / 128, NCOL / 128), dim3(256), 0, stream>>>(
            Xhi, Xlo, Wt, bq, bv, Q, K, V, b0, nTok);
        check_gemm<<<dim3(6, NCOL / 64), dim3(256), 0, stream>>>(
            hs, Wtf, bq, bv, Q, K, V, b0, nTok, flag);
        repair_gemm<<<dim3((nTok + 63) / 64, NCOL / 64), dim3(256), 0, stream>>>(
            hs, Wtf, bq, bv, Q, K, V, b0, nTok, flag);
        cls_attn<<<dim3(12 * cb), dim3(256), 0, stream>>>(Q, K, V, rel, rpi, out, b0);
        loc_attn<<<dim3(32, 12, cb), dim3(256), 0, stream>>>(Q, K, V, rel, rpi, rnd, out, b0);
    }
}